// Round 14
// baseline (3577.749 us; speedup 1.0000x reference)
//
#include <hip/hip_runtime.h>
#include <math.h>

#define B_SZ 128
#define T_SZ 256
#define DIN  128
#define HID  256
#define H2   512
#define NCLS 250

typedef float    f32x4 __attribute__((ext_vector_type(4)));
typedef unsigned u32x4 __attribute__((ext_vector_type(4)));

// ---- device-coherent 16B ops (sc0 sc1 = proven agent visibility) ----------
__device__ __forceinline__ void tg_load1(const unsigned* p, u32x4& a) {
    asm volatile("global_load_dwordx4 %0, %1, off sc0 sc1\n\t"
                 "s_waitcnt vmcnt(0)"
                 : "=&v"(a) : "v"(p) : "memory");
}
__device__ __forceinline__ void tg_store4(unsigned* p, u32x4 v) {
    asm volatile("global_store_dwordx4 %0, %1, off sc0 sc1" :: "v"(p), "v"(v) : "memory");
}

// tagged poll with exponential backoff: immediate try, then sleep 1,2,4,4...
// (s_sleep quantum ~64 cyc; keeps spin traffic off the coherent path)
__device__ __forceinline__ u32x4 tag_poll16(const unsigned* pp, unsigned tgv) {
    u32x4 va;
    tg_load1(pp, va);
    if ((((va.x^tgv)|(va.y^tgv)|(va.z^tgv)|(va.w^tgv)) & 3u) == 0u) return va;
    __builtin_amdgcn_s_sleep(1);
    tg_load1(pp, va);
    if ((((va.x^tgv)|(va.y^tgv)|(va.z^tgv)|(va.w^tgv)) & 3u) == 0u) return va;
    for (;;) {
        __builtin_amdgcn_s_sleep(2);
        tg_load1(pp, va);
        if ((((va.x^tgv)|(va.y^tgv)|(va.z^tgv)|(va.w^tgv)) & 3u) == 0u) return va;
        __builtin_amdgcn_s_sleep(4);
        tg_load1(pp, va);
        if ((((va.x^tgv)|(va.y^tgv)|(va.z^tgv)|(va.w^tgv)) & 3u) == 0u) return va;
    }
}

#define ACC4(A, Wp, v) \
    A = fmaf((v).x, (Wp)[0], A); A = fmaf((v).y, (Wp)[1], A); \
    A = fmaf((v).z, (Wp)[2], A); A = fmaf((v).w, (Wp)[3], A)

// 1024 WGs (l0): XCD slot = wg&7; member = (wg>>3)&15; g = (wg&7)*8 + (wg>>7).
__device__ __forceinline__ void group_decode_1024(int wg, int& g, int& member) {
    member = (wg >> 3) & 15;
    g = (wg & 7) * 8 + (wg >> 7);
}
// 512 WGs (l1): 32 groups x 16 members, 4 groups per XCD slot.
__device__ __forceinline__ void group_decode_512(int wg, int& g, int& member) {
    member = (wg >> 3) & 15;
    g = (wg & 7) * 4 + (wg >> 7);
}

// ---------------- L0: one dir per WG, 4-row groups, fused x-GEMM ------------
// 64 groups = dir(2) x bt(32 tiles of 4 rows); member = hct (16 cols).
__global__ __launch_bounds__(256, 4) void l0_scan(
    const float* __restrict__ x,
    const float* __restrict__ wihf, const float* __restrict__ bihf,
    const float* __restrict__ whhf, const float* __restrict__ bhhf,
    const float* __restrict__ wihb, const float* __restrict__ bihb,
    const float* __restrict__ whhb, const float* __restrict__ bhhb,
    unsigned* __restrict__ thb,   // [2 dir][2 par][B][HID] tagged
    float* __restrict__ h1)       // [B][T][512]
{
    __shared__ float hlds[4][256];
    __shared__ float xlds[2][4][128];
    __shared__ float hst[4][20];
    const int tid = threadIdx.x;
    int g, member;
    group_decode_1024(blockIdx.x, g, member);
    const int dir = g >> 5;
    const int b0  = (g & 31) * 4;
    const int hct = member;
    const int hc = tid >> 4, ks = tid & 15, ks4 = ks * 4;
    const int hcg = hct * 16 + hc;

    const float* wih = dir ? wihb : wihf;
    const float* bih = dir ? bihb : bihf;
    const float* whh = dir ? whhb : whhf;
    const float* bhh = dir ? bhhb : bhhf;

    float Wr[3][16], Wx[3][8];
#pragma unroll
    for (int gg = 0; gg < 3; ++gg) {
#pragma unroll
        for (int j = 0; j < 4; ++j) {
            float4 wv = *(const float4*)(whh + (size_t)(gg * HID + hcg) * HID + j * 64 + ks4);
            Wr[gg][4 * j] = wv.x; Wr[gg][4 * j + 1] = wv.y; Wr[gg][4 * j + 2] = wv.z; Wr[gg][4 * j + 3] = wv.w;
        }
#pragma unroll
        for (int j = 0; j < 2; ++j) {
            float4 wv = *(const float4*)(wih + (size_t)(gg * HID + hcg) * DIN + j * 64 + ks4);
            Wx[gg][4 * j] = wv.x; Wx[gg][4 * j + 1] = wv.y; Wx[gg][4 * j + 2] = wv.z; Wx[gg][4 * j + 3] = wv.w;
        }
    }
    const float sbr = bih[hcg] + bhh[hcg];
    const float sbz = bih[HID + hcg] + bhh[HID + hcg];
    const float bxn = bih[2 * HID + hcg];
    const float bhn = bhh[2 * HID + hcg];

    unsigned* hb = thb + (size_t)dir * 2 * B_SZ * HID;
    const int xr_ = tid >> 5, xc = (tid & 31) * 4;   // x-staging (4x128, tid<128)
    const int prw = tid >> 6, pc0 = (tid & 63) * 4;  // h poll (4x256, 16B/thr)

    // ---- prologue: stage x(0), prefetch x(1), xsum(0)
    float4 xp;
    if (tid < 128) {
        const int tg0 = dir ? (T_SZ - 1) : 0;
        xp = *(const float4*)(x + ((size_t)(b0 + xr_) * T_SZ + tg0) * DIN + xc);
        *(float4*)&xlds[0][xr_][xc] = xp;
    }
    __syncthreads();
    if (tid < 128) {
        const int tg1 = dir ? (T_SZ - 2) : 1;
        xp = *(const float4*)(x + ((size_t)(b0 + xr_) * T_SZ + tg1) * DIN + xc);
    }
    float xsr[4], xsz[4], xsn[4];
#pragma unroll
    for (int b = 0; b < 4; ++b) { xsr[b] = 0.f; xsz[b] = 0.f; xsn[b] = 0.f; }
#pragma unroll
    for (int b = 0; b < 4; ++b)
#pragma unroll
        for (int j = 0; j < 2; ++j) {
            float4 xv = *(const float4*)&xlds[0][b][j * 64 + ks4];
            ACC4(xsr[b], &Wx[0][4 * j], xv);
            ACC4(xsz[b], &Wx[1][4 * j], xv);
            ACC4(xsn[b], &Wx[2][4 * j], xv);
        }
#pragma unroll
    for (int m = 1; m <= 8; m <<= 1)
#pragma unroll
        for (int b = 0; b < 4; ++b) {
            xsr[b] += __shfl_xor(xsr[b], m, 64);
            xsz[b] += __shfl_xor(xsz[b], m, 64);
            xsn[b] += __shfl_xor(xsn[b], m, 64);
        }

    for (int t = 0; t < T_SZ; ++t) {
        const int tg = dir ? (T_SZ - 1 - t) : t;
        const unsigned* hp_t = hb + (size_t)(t & 1) * B_SZ * HID;
        unsigned* hn_t       = hb + (size_t)((t + 1) & 1) * B_SZ * HID;
        const unsigned tgv = (unsigned)(t & 3);
        const unsigned wtv = (unsigned)((t + 1) & 3);

        {   // tagged poll with backoff: own 4 h values (16B)
            u32x4 va = tag_poll16(hp_t + (size_t)(b0 + prw) * HID + pc0, tgv);
            *(u32x4*)&hlds[prw][pc0] = va;
        }
        if (tid < 128)
            *(float4*)&xlds[(t + 1) & 1][xr_][xc] = xp;   // stage x(t+1)
        __syncthreads();                                   // SYNC1

        if (tid < 128) {   // prefetch x(t+2)
            const int tn  = (t + 2 < T_SZ) ? (t + 2) : (T_SZ - 1);
            const int tgn = dir ? (T_SZ - 1 - tn) : tn;
            xp = *(const float4*)(x + ((size_t)(b0 + xr_) * T_SZ + tgn) * DIN + xc);
        }

        float aR[4], aZ[4], aH[4];
#pragma unroll
        for (int b = 0; b < 4; ++b) { aR[b] = 0.f; aZ[b] = 0.f; aH[b] = 0.f; }
#pragma unroll
        for (int b = 0; b < 4; ++b)
#pragma unroll
            for (int j = 0; j < 4; ++j) {
                float4 hv4 = *(const float4*)&hlds[b][j * 64 + ks4];
                ACC4(aR[b], &Wr[0][4 * j], hv4);
                ACC4(aZ[b], &Wr[1][4 * j], hv4);
                ACC4(aH[b], &Wr[2][4 * j], hv4);
            }
#pragma unroll
        for (int m = 1; m <= 8; m <<= 1)
#pragma unroll
            for (int b = 0; b < 4; ++b) {
                aR[b] += __shfl_xor(aR[b], m, 64);
                aZ[b] += __shfl_xor(aZ[b], m, 64);
                aH[b] += __shfl_xor(aH[b], m, 64);
            }

        if (ks < 4) {   // lane ks owns batch row b0+ks
            float sr = 0.f, sz = 0.f, sh = 0.f, xr = 0.f, xz = 0.f, xn = 0.f;
#pragma unroll
            for (int b = 0; b < 4; ++b)
                if (b == ks) { sr = aR[b]; sz = aZ[b]; sh = aH[b];
                               xr = xsr[b]; xz = xsz[b]; xn = xsn[b]; }
            const float hp = hlds[ks][hcg];
            const float r = 1.f / (1.f + expf(-(sr + xr + sbr)));
            const float z = 1.f / (1.f + expf(-(sz + xz + sbz)));
            const float n = tanhf(xn + bxn + r * (sh + bhn));
            hst[ks][hc] = (1.f - z) * n + z * hp;
        }
        __syncthreads();                                   // SYNC2
        if (tid < 16) {   // pack tagged h-state (4x16) + h1 store
            const int sr_ = tid >> 2, sc_ = (tid & 3) * 4;
            float4 hv4 = *(const float4*)&hst[sr_][sc_];
            u32x4 w;
            w.x = (__float_as_uint(hv4.x) & ~3u) | wtv;
            w.y = (__float_as_uint(hv4.y) & ~3u) | wtv;
            w.z = (__float_as_uint(hv4.z) & ~3u) | wtv;
            w.w = (__float_as_uint(hv4.w) & ~3u) | wtv;
            tg_store4(hn_t + (size_t)(b0 + sr_) * HID + hct * 16 + sc_, w);
            *(float4*)(h1 + ((size_t)(b0 + sr_) * T_SZ + tg) * H2 + dir * HID + hct * 16 + sc_) = hv4;
        }

        // shadow: xsum(t+1) (hides store visibility latency)
#pragma unroll
        for (int b = 0; b < 4; ++b) { xsr[b] = 0.f; xsz[b] = 0.f; xsn[b] = 0.f; }
#pragma unroll
        for (int b = 0; b < 4; ++b)
#pragma unroll
            for (int j = 0; j < 2; ++j) {
                float4 xv = *(const float4*)&xlds[(t + 1) & 1][b][j * 64 + ks4];
                ACC4(xsr[b], &Wx[0][4 * j], xv);
                ACC4(xsz[b], &Wx[1][4 * j], xv);
                ACC4(xsn[b], &Wx[2][4 * j], xv);
            }
#pragma unroll
        for (int m = 1; m <= 8; m <<= 1)
#pragma unroll
            for (int b = 0; b < 4; ++b) {
                xsr[b] += __shfl_xor(xsr[b], m, 64);
                xsz[b] += __shfl_xor(xsz[b], m, 64);
                xsn[b] += __shfl_xor(xsn[b], m, 64);
            }
    }
}

// ---------------- L1 forward: 4-row groups, fused x-GEMM (Din=512) ----------
// 32 groups = bt(32 tiles of 4 rows); member = hct.
__global__ __launch_bounds__(256, 2) void l1_scan(
    const float* __restrict__ h1,
    const float* __restrict__ wih, const float* __restrict__ bih,
    const float* __restrict__ whh, const float* __restrict__ bhh,
    unsigned* __restrict__ thb)   // [2 par][B][HID] tagged
{
    __shared__ float hlds[4][256];
    __shared__ float xlds[2][4][512];
    __shared__ float hst[4][20];
    const int tid = threadIdx.x;
    int g, member;
    group_decode_512(blockIdx.x, g, member);
    const int b0  = g * 4;
    const int hct = member;
    const int hc = tid >> 4, ks = tid & 15, ks4 = ks * 4;
    const int hcg = hct * 16 + hc;

    float Wr[3][16], Wx[3][32];
#pragma unroll
    for (int gg = 0; gg < 3; ++gg) {
#pragma unroll
        for (int j = 0; j < 4; ++j) {
            float4 wv = *(const float4*)(whh + (size_t)(gg * HID + hcg) * HID + j * 64 + ks4);
            Wr[gg][4 * j] = wv.x; Wr[gg][4 * j + 1] = wv.y; Wr[gg][4 * j + 2] = wv.z; Wr[gg][4 * j + 3] = wv.w;
        }
#pragma unroll
        for (int j = 0; j < 8; ++j) {
            float4 wv = *(const float4*)(wih + (size_t)(gg * HID + hcg) * H2 + j * 64 + ks4);
            Wx[gg][4 * j] = wv.x; Wx[gg][4 * j + 1] = wv.y; Wx[gg][4 * j + 2] = wv.z; Wx[gg][4 * j + 3] = wv.w;
        }
    }
    const float sbr = bih[hcg] + bhh[hcg];
    const float sbz = bih[HID + hcg] + bhh[HID + hcg];
    const float bxn = bih[2 * HID + hcg];
    const float bhn = bhh[2 * HID + hcg];

    const int r4 = tid >> 6, s64 = (tid & 63) * 4;   // x-staging (4x512, 2x16B/thr)
    const int prw = tid >> 6, pc0 = (tid & 63) * 4;  // h poll (4x256, 16B/thr)

    float4 xp[2];
    {
        const float* xsrc = h1 + ((size_t)(b0 + r4) * T_SZ + 0) * H2;
        xp[0] = *(const float4*)(xsrc + s64);
        xp[1] = *(const float4*)(xsrc + 256 + s64);
        *(float4*)&xlds[0][r4][s64]       = xp[0];
        *(float4*)&xlds[0][r4][256 + s64] = xp[1];
    }
    __syncthreads();
    {
        const float* xsrc = h1 + ((size_t)(b0 + r4) * T_SZ + 1) * H2;
        xp[0] = *(const float4*)(xsrc + s64);
        xp[1] = *(const float4*)(xsrc + 256 + s64);
    }
    float xsr[4], xsz[4], xsn[4];
#pragma unroll
    for (int b = 0; b < 4; ++b) { xsr[b] = 0.f; xsz[b] = 0.f; xsn[b] = 0.f; }
#pragma unroll
    for (int b = 0; b < 4; ++b)
#pragma unroll
        for (int j = 0; j < 8; ++j) {
            float4 xv = *(const float4*)&xlds[0][b][j * 64 + ks4];
            ACC4(xsr[b], &Wx[0][4 * j], xv);
            ACC4(xsz[b], &Wx[1][4 * j], xv);
            ACC4(xsn[b], &Wx[2][4 * j], xv);
        }
#pragma unroll
    for (int m = 1; m <= 8; m <<= 1)
#pragma unroll
        for (int b = 0; b < 4; ++b) {
            xsr[b] += __shfl_xor(xsr[b], m, 64);
            xsz[b] += __shfl_xor(xsz[b], m, 64);
            xsn[b] += __shfl_xor(xsn[b], m, 64);
        }

    for (int t = 0; t < T_SZ; ++t) {
        const unsigned* hp_t = thb + (size_t)(t & 1) * B_SZ * HID;
        unsigned* hn_t       = thb + (size_t)((t + 1) & 1) * B_SZ * HID;
        const unsigned tgv = (unsigned)(t & 3);
        const unsigned wtv = (unsigned)((t + 1) & 3);

        {   // tagged poll with backoff: own 4 h values (16B)
            u32x4 va = tag_poll16(hp_t + (size_t)(b0 + prw) * HID + pc0, tgv);
            *(u32x4*)&hlds[prw][pc0] = va;
        }
        *(float4*)&xlds[(t + 1) & 1][r4][s64]       = xp[0];
        *(float4*)&xlds[(t + 1) & 1][r4][256 + s64] = xp[1];
        __syncthreads();                               // SYNC1

        {   // prefetch x(t+2) from h1
            const int tn = (t + 2 < T_SZ) ? (t + 2) : (T_SZ - 1);
            const float* xsrc = h1 + ((size_t)(b0 + r4) * T_SZ + tn) * H2;
            xp[0] = *(const float4*)(xsrc + s64);
            xp[1] = *(const float4*)(xsrc + 256 + s64);
        }

        float aR[4], aZ[4], aH[4];
#pragma unroll
        for (int b = 0; b < 4; ++b) { aR[b] = 0.f; aZ[b] = 0.f; aH[b] = 0.f; }
#pragma unroll
        for (int b = 0; b < 4; ++b)
#pragma unroll
            for (int j = 0; j < 4; ++j) {
                float4 hv4 = *(const float4*)&hlds[b][j * 64 + ks4];
                ACC4(aR[b], &Wr[0][4 * j], hv4);
                ACC4(aZ[b], &Wr[1][4 * j], hv4);
                ACC4(aH[b], &Wr[2][4 * j], hv4);
            }
#pragma unroll
        for (int m = 1; m <= 8; m <<= 1)
#pragma unroll
            for (int b = 0; b < 4; ++b) {
                aR[b] += __shfl_xor(aR[b], m, 64);
                aZ[b] += __shfl_xor(aZ[b], m, 64);
                aH[b] += __shfl_xor(aH[b], m, 64);
            }

        if (ks < 4) {   // lane ks owns row b0+ks
            float sr = 0.f, sz = 0.f, sh = 0.f, xr = 0.f, xz = 0.f, xn = 0.f;
#pragma unroll
            for (int b = 0; b < 4; ++b)
                if (b == ks) { sr = aR[b]; sz = aZ[b]; sh = aH[b];
                               xr = xsr[b]; xz = xsz[b]; xn = xsn[b]; }
            const float hp = hlds[ks][hcg];
            const float r = 1.f / (1.f + expf(-(sr + xr + sbr)));
            const float z = 1.f / (1.f + expf(-(sz + xz + sbz)));
            const float n = tanhf(xn + bxn + r * (sh + bhn));
            hst[ks][hc] = (1.f - z) * n + z * hp;
        }
        __syncthreads();                               // SYNC2
        if (tid < 16) {   // pack tagged h-state (4x16)
            const int sr_ = tid >> 2, sc_ = (tid & 3) * 4;
            float4 hv4 = *(const float4*)&hst[sr_][sc_];
            u32x4 w;
            w.x = (__float_as_uint(hv4.x) & ~3u) | wtv;
            w.y = (__float_as_uint(hv4.y) & ~3u) | wtv;
            w.z = (__float_as_uint(hv4.z) & ~3u) | wtv;
            w.w = (__float_as_uint(hv4.w) & ~3u) | wtv;
            tg_store4(hn_t + (size_t)(b0 + sr_) * HID + hct * 16 + sc_, w);
        }

        // shadow: x-part(t+1)
#pragma unroll
        for (int b = 0; b < 4; ++b) { xsr[b] = 0.f; xsz[b] = 0.f; xsn[b] = 0.f; }
#pragma unroll
        for (int b = 0; b < 4; ++b)
#pragma unroll
            for (int j = 0; j < 8; ++j) {
                float4 xv = *(const float4*)&xlds[(t + 1) & 1][b][j * 64 + ks4];
                ACC4(xsr[b], &Wx[0][4 * j], xv);
                ACC4(xsz[b], &Wx[1][4 * j], xv);
                ACC4(xsn[b], &Wx[2][4 * j], xv);
            }
#pragma unroll
        for (int m = 1; m <= 8; m <<= 1)
#pragma unroll
            for (int b = 0; b < 4; ++b) {
                xsr[b] += __shfl_xor(xsr[b], m, 64);
                xsz[b] += __shfl_xor(xsz[b], m, 64);
                xsn[b] += __shfl_xor(xsn[b], m, 64);
            }
    }
}

// ---------------- L1 backward: only t=T-1 consumed -> one step from h0=0 ----
__global__ __launch_bounds__(256) void l1r_laststep(
    const float* __restrict__ h1, const float* __restrict__ wih,
    const float* __restrict__ bih, const float* __restrict__ bhh,
    float* __restrict__ h2b)
{
    const int tid = threadIdx.x;
    const int b  = (blockIdx.x >> 4) * 16 + (tid >> 4);
    const int hc = (blockIdx.x & 15) * 16 + (tid & 15);
    const float* hrow = h1 + ((size_t)b * T_SZ + (T_SZ - 1)) * H2;
    float ar = 0.f, az = 0.f, an = 0.f;
#pragma unroll 8
    for (int k = 0; k < H2; k += 4) {
        float4 hv = *(const float4*)(hrow + k);
        float4 wr = *(const float4*)(wih + (size_t)hc * H2 + k);
        float4 wz = *(const float4*)(wih + (size_t)(HID + hc) * H2 + k);
        float4 wn = *(const float4*)(wih + (size_t)(2 * HID + hc) * H2 + k);
        ar = fmaf(hv.x, wr.x, fmaf(hv.y, wr.y, fmaf(hv.z, wr.z, fmaf(hv.w, wr.w, ar))));
        az = fmaf(hv.x, wz.x, fmaf(hv.y, wz.y, fmaf(hv.z, wz.z, fmaf(hv.w, wz.w, az))));
        an = fmaf(hv.x, wn.x, fmaf(hv.y, wn.y, fmaf(hv.z, wn.z, fmaf(hv.w, wn.w, an))));
    }
    float r = 1.f / (1.f + expf(-(ar + bih[hc] + bhh[hc])));
    float z = 1.f / (1.f + expf(-(az + bih[HID + hc] + bhh[HID + hc])));
    float n = tanhf(an + bih[2 * HID + hc] + r * bhh[2 * HID + hc]);
    h2b[(size_t)b * HID + hc] = (1.f - z) * n;
}

// ---------------- LayerNorm + head ----------------
__global__ __launch_bounds__(256) void ln_head(
    const float* __restrict__ h2f, const float* __restrict__ h2b,
    const float* __restrict__ g, const float* __restrict__ be,
    const float* __restrict__ hw, const float* __restrict__ hb,
    float* __restrict__ out)
{
    __shared__ float v[H2];
    __shared__ float rbuf[8];
    const int b = blockIdx.x, tid = threadIdx.x;
    float xa = h2f[(size_t)b * HID + tid];
    float xb = h2b[(size_t)b * HID + tid];
    float s = xa + xb;
#pragma unroll
    for (int m = 32; m >= 1; m >>= 1) s += __shfl_xor(s, m, 64);
    if ((tid & 63) == 0) rbuf[tid >> 6] = s;
    __syncthreads();
    float mu = (rbuf[0] + rbuf[1] + rbuf[2] + rbuf[3]) * (1.0f / H2);
    float da = xa - mu, db = xb - mu;
    float q = da * da + db * db;
#pragma unroll
    for (int m = 32; m >= 1; m >>= 1) q += __shfl_xor(q, m, 64);
    __syncthreads();
    if ((tid & 63) == 0) rbuf[tid >> 6] = q;
    __syncthreads();
    float var = (rbuf[0] + rbuf[1] + rbuf[2] + rbuf[3]) * (1.0f / H2);
    float rs = rsqrtf(var + 1e-5f);
    v[tid]       = da * rs * g[tid] + be[tid];
    v[HID + tid] = db * rs * g[HID + tid] + be[HID + tid];
    __syncthreads();
    if (tid < NCLS) {
        float a = hb[tid];
        const float* wr = hw + (size_t)tid * H2;
#pragma unroll 4
        for (int k = 0; k < H2; k += 4) {
            float4 wv = *(const float4*)(wr + k);
            a = fmaf(v[k], wv.x, fmaf(v[k + 1], wv.y, fmaf(v[k + 2], wv.z, fmaf(v[k + 3], wv.w, a))));
        }
        out[(size_t)b * NCLS + tid] = a;
    }
}

// ---------------- host ----------------
extern "C" void kernel_launch(void* const* d_in, const int* in_sizes, int n_in,
                              void* d_out, int out_size, void* d_ws, size_t ws_size,
                              hipStream_t stream)
{
    const float* x     = (const float*)d_in[0];
    const float* wih0f = (const float*)d_in[1];
    const float* whh0f = (const float*)d_in[2];
    const float* bih0f = (const float*)d_in[3];
    const float* bhh0f = (const float*)d_in[4];
    const float* wih0b = (const float*)d_in[5];
    const float* whh0b = (const float*)d_in[6];
    const float* bih0b = (const float*)d_in[7];
    const float* bhh0b = (const float*)d_in[8];
    const float* wih1f = (const float*)d_in[9];
    const float* whh1f = (const float*)d_in[10];
    const float* bih1f = (const float*)d_in[11];
    const float* bhh1f = (const float*)d_in[12];
    const float* wih1b = (const float*)d_in[13];
    const float* whh1b = (const float*)d_in[14];
    const float* bih1b = (const float*)d_in[15];
    const float* bhh1b = (const float*)d_in[16];
    const float* lng   = (const float*)d_in[17];
    const float* lnb   = (const float*)d_in[18];
    const float* hw    = (const float*)d_in[19];
    const float* hbb   = (const float*)d_in[20];

    char* wsb = (char*)d_ws;
    size_t off = 0;
    auto alloc = [&](size_t bytes) -> void* {
        void* p = (void*)(wsb + off);
        off += (bytes + 255) & ~(size_t)255;
        return p;
    };
    unsigned* thbA = (unsigned*)alloc((size_t)2 * 2 * B_SZ * HID * 4);   // 1 MB tagged
    unsigned* thbB = (unsigned*)alloc((size_t)2 * B_SZ * HID * 4);       // 512 KB tagged
    size_t zspan = off;
    float* h2b = (float*)alloc((size_t)B_SZ * HID * 4);
    float* h1  = (float*)alloc((size_t)B_SZ * T_SZ * H2 * 4);            // 64 MB

    // zero tagged buffers: tag 0 == "h(0)=0 valid" (re-runs on every replay)
    (void)hipMemsetAsync(d_ws, 0, zspan, stream);

    l0_scan<<<dim3(1024), dim3(256), 0, stream>>>(
        x, wih0f, bih0f, whh0f, bhh0f, wih0b, bih0b, whh0b, bhh0b, thbA, h1);

    l1r_laststep<<<dim3(128), dim3(256), 0, stream>>>(h1, wih1b, bih1b, bhh1b, h2b);

    l1_scan<<<dim3(512), dim3(256), 0, stream>>>(
        h1, wih1f, bih1f, whh1f, bhh1f, thbB);

    // L1-fwd final h lands in parity 0 (t=255 writes (255+1)&1 == 0); tags are 0 bits
    ln_head<<<dim3(B_SZ), dim3(256), 0, stream>>>(
        (const float*)thbB, h2b, lng, lnb, hw, hbb, (float*)d_out);
}

// Round 15
// 2839.539 us; speedup vs baseline: 1.2600x; 1.2600x over previous
//
#include <hip/hip_runtime.h>
#include <math.h>

#define B_SZ 128
#define T_SZ 256
#define DIN  128
#define HID  256
#define H2   512
#define NCLS 250

typedef float    f32x4 __attribute__((ext_vector_type(4)));
typedef unsigned u32x4 __attribute__((ext_vector_type(4)));

// ---- device-coherent 16B ops (sc0 sc1 = proven agent visibility) ----------
__device__ __forceinline__ void tg_load1(const unsigned* p, u32x4& a) {
    asm volatile("global_load_dwordx4 %0, %1, off sc0 sc1\n\t"
                 "s_waitcnt vmcnt(0)"
                 : "=&v"(a) : "v"(p) : "memory");
}
__device__ __forceinline__ void tg_load1_async(const unsigned* p, u32x4& a) {
    asm volatile("global_load_dwordx4 %0, %1, off sc0 sc1"
                 : "=&v"(a) : "v"(p) : "memory");
}
// two 16B spans 512B apart (l0 poll map: cols c..c+3 and c+128..c+131)
__device__ __forceinline__ void tg_load2_split(const unsigned* p, u32x4& a, u32x4& b) {
    asm volatile("global_load_dwordx4 %0, %2, off sc0 sc1\n\t"
                 "global_load_dwordx4 %1, %2, off offset:512 sc0 sc1\n\t"
                 "s_waitcnt vmcnt(0)"
                 : "=&v"(a), "=&v"(b) : "v"(p) : "memory");
}
__device__ __forceinline__ void tg_load2_split_async(const unsigned* p, u32x4& a, u32x4& b) {
    asm volatile("global_load_dwordx4 %0, %2, off sc0 sc1\n\t"
                 "global_load_dwordx4 %1, %2, off offset:512 sc0 sc1"
                 : "=&v"(a), "=&v"(b) : "v"(p) : "memory");
}
__device__ __forceinline__ void tg_store4(unsigned* p, u32x4 v) {
    asm volatile("global_store_dwordx4 %0, %1, off sc0 sc1" :: "v"(p), "v"(v) : "memory");
}
// waitcnt with register binding: ties the loaded values to the wait so the
// compiler cannot hoist their uses above it (rule-18-safe).
__device__ __forceinline__ void wait_bind1(u32x4& a) {
    asm volatile("s_waitcnt vmcnt(0)" : "+v"(a) :: "memory");
}
__device__ __forceinline__ void wait_bind2(u32x4& a, u32x4& b) {
    asm volatile("s_waitcnt vmcnt(0)" : "+v"(a), "+v"(b) :: "memory");
}

#define ACC4(A, Wp, v) \
    A = fmaf((v).x, (Wp)[0], A); A = fmaf((v).y, (Wp)[1], A); \
    A = fmaf((v).z, (Wp)[2], A); A = fmaf((v).w, (Wp)[3], A)

// 512 WGs: XCD slot = wg&7; member = (wg>>3)&15; group = (wg&7)*4 + (wg>>7).
__device__ __forceinline__ void group_decode(int wg, int& g, int& member) {
    member = (wg >> 3) & 15;
    g = (wg & 7) * 4 + (wg >> 7);
}

// ---------------- L0: one dir per WG, 8-row groups, fused x-GEMM ------------
// 32 groups = dir(2) x bt(16 tiles of 8 rows); member = hct (16 cols).
__global__ __launch_bounds__(256, 2) void l0_scan(
    const float* __restrict__ x,
    const float* __restrict__ wihf, const float* __restrict__ bihf,
    const float* __restrict__ whhf, const float* __restrict__ bhhf,
    const float* __restrict__ wihb, const float* __restrict__ bihb,
    const float* __restrict__ whhb, const float* __restrict__ bhhb,
    unsigned* __restrict__ thb,   // [2 dir][2 par][B][HID] tagged
    float* __restrict__ h1)       // [B][T][512]
{
    __shared__ float hlds[8][256];
    __shared__ float xlds[2][8][128];
    __shared__ float hst[8][20];
    const int tid = threadIdx.x;
    int g, member;
    group_decode(blockIdx.x, g, member);
    const int dir = g >> 4;
    const int b0  = (g & 15) * 8;
    const int hct = member;
    const int hc = tid >> 4, ks = tid & 15, ks4 = ks * 4;
    const int hcg = hct * 16 + hc;

    const float* wih = dir ? wihb : wihf;
    const float* bih = dir ? bihb : bihf;
    const float* whh = dir ? whhb : whhf;
    const float* bhh = dir ? bhhb : bhhf;

    float Wr[3][16], Wx[3][8];
#pragma unroll
    for (int gg = 0; gg < 3; ++gg) {
#pragma unroll
        for (int j = 0; j < 4; ++j) {
            float4 wv = *(const float4*)(whh + (size_t)(gg * HID + hcg) * HID + j * 64 + ks4);
            Wr[gg][4 * j] = wv.x; Wr[gg][4 * j + 1] = wv.y; Wr[gg][4 * j + 2] = wv.z; Wr[gg][4 * j + 3] = wv.w;
        }
#pragma unroll
        for (int j = 0; j < 2; ++j) {
            float4 wv = *(const float4*)(wih + (size_t)(gg * HID + hcg) * DIN + j * 64 + ks4);
            Wx[gg][4 * j] = wv.x; Wx[gg][4 * j + 1] = wv.y; Wx[gg][4 * j + 2] = wv.z; Wx[gg][4 * j + 3] = wv.w;
        }
    }
    const float sbr = bih[hcg] + bhh[hcg];
    const float sbz = bih[HID + hcg] + bhh[HID + hcg];
    const float bxn = bih[2 * HID + hcg];
    const float bhn = bhh[2 * HID + hcg];

    unsigned* hb = thb + (size_t)dir * 2 * B_SZ * HID;
    const int r8 = tid >> 5, c32 = (tid & 31) * 4;   // x-staging (8x128, 16B/thr)
    const int prow = tid >> 5, pc4 = (tid & 31) * 4; // h poll: 16B at +0 and +512B

    // ---- prologue: stage x(0), prefetch x(1), xsum(0)
    float4 xp;
    {
        const int tg0 = dir ? (T_SZ - 1) : 0;
        xp = *(const float4*)(x + ((size_t)(b0 + r8) * T_SZ + tg0) * DIN + c32);
        *(float4*)&xlds[0][r8][c32] = xp;
    }
    __syncthreads();
    {
        const int tg1 = dir ? (T_SZ - 2) : 1;
        xp = *(const float4*)(x + ((size_t)(b0 + r8) * T_SZ + tg1) * DIN + c32);
    }
    float xsr[8], xsz[8], xsn[8];
#pragma unroll
    for (int b = 0; b < 8; ++b) { xsr[b] = 0.f; xsz[b] = 0.f; xsn[b] = 0.f; }
#pragma unroll
    for (int b = 0; b < 8; ++b)
#pragma unroll
        for (int j = 0; j < 2; ++j) {
            float4 xv = *(const float4*)&xlds[0][b][j * 64 + ks4];
            ACC4(xsr[b], &Wx[0][4 * j], xv);
            ACC4(xsz[b], &Wx[1][4 * j], xv);
            ACC4(xsn[b], &Wx[2][4 * j], xv);
        }
#pragma unroll
    for (int m = 1; m <= 8; m <<= 1)
#pragma unroll
        for (int b = 0; b < 8; ++b) {
            xsr[b] += __shfl_xor(xsr[b], m, 64);
            xsz[b] += __shfl_xor(xsz[b], m, 64);
            xsn[b] += __shfl_xor(xsn[b], m, 64);
        }

    // early poll issue for t=0 (parity 0 buffer; zeroed -> tag 0 matches)
    u32x4 va, vb;
    tg_load2_split_async(hb + (size_t)(b0 + prow) * HID + pc4, va, vb);

    for (int t = 0; t < T_SZ; ++t) {
        const int tg = dir ? (T_SZ - 1 - t) : t;
        const unsigned* hp_t = hb + (size_t)(t & 1) * B_SZ * HID;
        unsigned* hn_t       = hb + (size_t)((t + 1) & 1) * B_SZ * HID;
        const unsigned tgv = (unsigned)(t & 3);
        const unsigned wtv = (unsigned)((t + 1) & 3);
        const unsigned* pp = hp_t + (size_t)(b0 + prow) * HID + pc4;

        {   // check early-issued poll; retry synchronously if not yet visible
            wait_bind2(va, vb);
            unsigned mm = (va.x^tgv)|(va.y^tgv)|(va.z^tgv)|(va.w^tgv)
                        | (vb.x^tgv)|(vb.y^tgv)|(vb.z^tgv)|(vb.w^tgv);
            while ((mm & 3u) != 0u) {
                tg_load2_split(pp, va, vb);
                mm = (va.x^tgv)|(va.y^tgv)|(va.z^tgv)|(va.w^tgv)
                   | (vb.x^tgv)|(vb.y^tgv)|(vb.z^tgv)|(vb.w^tgv);
            }
            *(u32x4*)&hlds[prow][pc4]       = va;
            *(u32x4*)&hlds[prow][pc4 + 128] = vb;
        }
        *(float4*)&xlds[(t + 1) & 1][r8][c32] = xp;   // stage x(t+1)
        __syncthreads();                               // SYNC1

        {   // prefetch x(t+2)
            const int tn  = (t + 2 < T_SZ) ? (t + 2) : (T_SZ - 1);
            const int tgn = dir ? (T_SZ - 1 - tn) : tn;
            xp = *(const float4*)(x + ((size_t)(b0 + r8) * T_SZ + tgn) * DIN + c32);
        }

        float aR[8], aZ[8], aH[8];
#pragma unroll
        for (int b = 0; b < 8; ++b) { aR[b] = 0.f; aZ[b] = 0.f; aH[b] = 0.f; }
#pragma unroll
        for (int b = 0; b < 8; ++b)
#pragma unroll
            for (int j = 0; j < 4; ++j) {
                float4 hv4 = *(const float4*)&hlds[b][j * 64 + ks4];
                ACC4(aR[b], &Wr[0][4 * j], hv4);
                ACC4(aZ[b], &Wr[1][4 * j], hv4);
                ACC4(aH[b], &Wr[2][4 * j], hv4);
            }
#pragma unroll
        for (int m = 1; m <= 8; m <<= 1)
#pragma unroll
            for (int b = 0; b < 8; ++b) {
                aR[b] += __shfl_xor(aR[b], m, 64);
                aZ[b] += __shfl_xor(aZ[b], m, 64);
                aH[b] += __shfl_xor(aH[b], m, 64);
            }

        if (ks < 8) {   // lane ks owns batch row b0+ks
            float sr = 0.f, sz = 0.f, sh = 0.f, xr = 0.f, xz = 0.f, xn = 0.f;
#pragma unroll
            for (int b = 0; b < 8; ++b)
                if (b == ks) { sr = aR[b]; sz = aZ[b]; sh = aH[b];
                               xr = xsr[b]; xz = xsz[b]; xn = xsn[b]; }
            const float hp = hlds[ks][hcg];
            const float r = 1.f / (1.f + expf(-(sr + xr + sbr)));
            const float z = 1.f / (1.f + expf(-(sz + xz + sbz)));
            const float n = tanhf(xn + bxn + r * (sh + bhn));
            hst[ks][hc] = (1.f - z) * n + z * hp;
        }
        __syncthreads();                               // SYNC2
        if (tid < 32) {   // pack tagged h-state (8x16) + h1 store
            const int sr_ = tid >> 2, sc_ = (tid & 3) * 4;
            float4 hv4 = *(const float4*)&hst[sr_][sc_];
            u32x4 w;
            w.x = (__float_as_uint(hv4.x) & ~3u) | wtv;
            w.y = (__float_as_uint(hv4.y) & ~3u) | wtv;
            w.z = (__float_as_uint(hv4.z) & ~3u) | wtv;
            w.w = (__float_as_uint(hv4.w) & ~3u) | wtv;
            tg_store4(hn_t + (size_t)(b0 + sr_) * HID + hct * 16 + sc_, w);
            *(float4*)(h1 + ((size_t)(b0 + sr_) * T_SZ + tg) * H2 + dir * HID + hct * 16 + sc_) = hv4;
        }

        // early poll issue for t+1 (flight hidden under x-shadow below)
        tg_load2_split_async(hn_t + (size_t)(b0 + prow) * HID + pc4, va, vb);

        // shadow: xsum(t+1)
#pragma unroll
        for (int b = 0; b < 8; ++b) { xsr[b] = 0.f; xsz[b] = 0.f; xsn[b] = 0.f; }
#pragma unroll
        for (int b = 0; b < 8; ++b)
#pragma unroll
            for (int j = 0; j < 2; ++j) {
                float4 xv = *(const float4*)&xlds[(t + 1) & 1][b][j * 64 + ks4];
                ACC4(xsr[b], &Wx[0][4 * j], xv);
                ACC4(xsz[b], &Wx[1][4 * j], xv);
                ACC4(xsn[b], &Wx[2][4 * j], xv);
            }
#pragma unroll
        for (int m = 1; m <= 8; m <<= 1)
#pragma unroll
            for (int b = 0; b < 8; ++b) {
                xsr[b] += __shfl_xor(xsr[b], m, 64);
                xsz[b] += __shfl_xor(xsz[b], m, 64);
                xsn[b] += __shfl_xor(xsn[b], m, 64);
            }
    }
}

// ---------------- L1 forward: 4-row groups, fused x-GEMM (Din=512) ----------
// 32 groups = bt(32 tiles of 4 rows); member = hct.
__global__ __launch_bounds__(256, 2) void l1_scan(
    const float* __restrict__ h1,
    const float* __restrict__ wih, const float* __restrict__ bih,
    const float* __restrict__ whh, const float* __restrict__ bhh,
    unsigned* __restrict__ thb)   // [2 par][B][HID] tagged
{
    __shared__ float hlds[4][256];
    __shared__ float xlds[2][4][512];
    __shared__ float hst[4][20];
    const int tid = threadIdx.x;
    int g, member;
    group_decode(blockIdx.x, g, member);
    const int b0  = g * 4;
    const int hct = member;
    const int hc = tid >> 4, ks = tid & 15, ks4 = ks * 4;
    const int hcg = hct * 16 + hc;

    float Wr[3][16], Wx[3][32];
#pragma unroll
    for (int gg = 0; gg < 3; ++gg) {
#pragma unroll
        for (int j = 0; j < 4; ++j) {
            float4 wv = *(const float4*)(whh + (size_t)(gg * HID + hcg) * HID + j * 64 + ks4);
            Wr[gg][4 * j] = wv.x; Wr[gg][4 * j + 1] = wv.y; Wr[gg][4 * j + 2] = wv.z; Wr[gg][4 * j + 3] = wv.w;
        }
#pragma unroll
        for (int j = 0; j < 8; ++j) {
            float4 wv = *(const float4*)(wih + (size_t)(gg * HID + hcg) * H2 + j * 64 + ks4);
            Wx[gg][4 * j] = wv.x; Wx[gg][4 * j + 1] = wv.y; Wx[gg][4 * j + 2] = wv.z; Wx[gg][4 * j + 3] = wv.w;
        }
    }
    const float sbr = bih[hcg] + bhh[hcg];
    const float sbz = bih[HID + hcg] + bhh[HID + hcg];
    const float bxn = bih[2 * HID + hcg];
    const float bhn = bhh[2 * HID + hcg];

    const int r4 = tid >> 6, s64 = (tid & 63) * 4;   // x-staging (4x512, 2x16B/thr)
    const int prw = tid >> 6, pc0 = (tid & 63) * 4;  // h poll (4x256, 16B/thr)

    float4 xp[2];
    {
        const float* xsrc = h1 + ((size_t)(b0 + r4) * T_SZ + 0) * H2;
        xp[0] = *(const float4*)(xsrc + s64);
        xp[1] = *(const float4*)(xsrc + 256 + s64);
        *(float4*)&xlds[0][r4][s64]       = xp[0];
        *(float4*)&xlds[0][r4][256 + s64] = xp[1];
    }
    __syncthreads();
    {
        const float* xsrc = h1 + ((size_t)(b0 + r4) * T_SZ + 1) * H2;
        xp[0] = *(const float4*)(xsrc + s64);
        xp[1] = *(const float4*)(xsrc + 256 + s64);
    }
    float xsr[4], xsz[4], xsn[4];
#pragma unroll
    for (int b = 0; b < 4; ++b) { xsr[b] = 0.f; xsz[b] = 0.f; xsn[b] = 0.f; }
#pragma unroll
    for (int b = 0; b < 4; ++b)
#pragma unroll
        for (int j = 0; j < 8; ++j) {
            float4 xv = *(const float4*)&xlds[0][b][j * 64 + ks4];
            ACC4(xsr[b], &Wx[0][4 * j], xv);
            ACC4(xsz[b], &Wx[1][4 * j], xv);
            ACC4(xsn[b], &Wx[2][4 * j], xv);
        }
#pragma unroll
    for (int m = 1; m <= 8; m <<= 1)
#pragma unroll
        for (int b = 0; b < 4; ++b) {
            xsr[b] += __shfl_xor(xsr[b], m, 64);
            xsz[b] += __shfl_xor(xsz[b], m, 64);
            xsn[b] += __shfl_xor(xsn[b], m, 64);
        }

    // early poll issue for t=0
    u32x4 va;
    tg_load1_async(thb + (size_t)(b0 + prw) * HID + pc0, va);

    for (int t = 0; t < T_SZ; ++t) {
        const unsigned* hp_t = thb + (size_t)(t & 1) * B_SZ * HID;
        unsigned* hn_t       = thb + (size_t)((t + 1) & 1) * B_SZ * HID;
        const unsigned tgv = (unsigned)(t & 3);
        const unsigned wtv = (unsigned)((t + 1) & 3);
        const unsigned* pp = hp_t + (size_t)(b0 + prw) * HID + pc0;

        {   // check early-issued poll; retry if stale
            wait_bind1(va);
            unsigned mm = (va.x^tgv)|(va.y^tgv)|(va.z^tgv)|(va.w^tgv);
            while ((mm & 3u) != 0u) {
                tg_load1(pp, va);
                mm = (va.x^tgv)|(va.y^tgv)|(va.z^tgv)|(va.w^tgv);
            }
            *(u32x4*)&hlds[prw][pc0] = va;
        }
        *(float4*)&xlds[(t + 1) & 1][r4][s64]       = xp[0];
        *(float4*)&xlds[(t + 1) & 1][r4][256 + s64] = xp[1];
        __syncthreads();                               // SYNC1

        {   // prefetch x(t+2) from h1
            const int tn = (t + 2 < T_SZ) ? (t + 2) : (T_SZ - 1);
            const float* xsrc = h1 + ((size_t)(b0 + r4) * T_SZ + tn) * H2;
            xp[0] = *(const float4*)(xsrc + s64);
            xp[1] = *(const float4*)(xsrc + 256 + s64);
        }

        float aR[4], aZ[4], aH[4];
#pragma unroll
        for (int b = 0; b < 4; ++b) { aR[b] = 0.f; aZ[b] = 0.f; aH[b] = 0.f; }
#pragma unroll
        for (int b = 0; b < 4; ++b)
#pragma unroll
            for (int j = 0; j < 4; ++j) {
                float4 hv4 = *(const float4*)&hlds[b][j * 64 + ks4];
                ACC4(aR[b], &Wr[0][4 * j], hv4);
                ACC4(aZ[b], &Wr[1][4 * j], hv4);
                ACC4(aH[b], &Wr[2][4 * j], hv4);
            }
#pragma unroll
        for (int m = 1; m <= 8; m <<= 1)
#pragma unroll
            for (int b = 0; b < 4; ++b) {
                aR[b] += __shfl_xor(aR[b], m, 64);
                aZ[b] += __shfl_xor(aZ[b], m, 64);
                aH[b] += __shfl_xor(aH[b], m, 64);
            }

        if (ks < 4) {   // lane ks owns row b0+ks
            float sr = 0.f, sz = 0.f, sh = 0.f, xr = 0.f, xz = 0.f, xn = 0.f;
#pragma unroll
            for (int b = 0; b < 4; ++b)
                if (b == ks) { sr = aR[b]; sz = aZ[b]; sh = aH[b];
                               xr = xsr[b]; xz = xsz[b]; xn = xsn[b]; }
            const float hp = hlds[ks][hcg];
            const float r = 1.f / (1.f + expf(-(sr + xr + sbr)));
            const float z = 1.f / (1.f + expf(-(sz + xz + sbz)));
            const float n = tanhf(xn + bxn + r * (sh + bhn));
            hst[ks][hc] = (1.f - z) * n + z * hp;
        }
        __syncthreads();                               // SYNC2
        if (tid < 16) {   // pack tagged h-state (4x16)
            const int sr_ = tid >> 2, sc_ = (tid & 3) * 4;
            float4 hv4 = *(const float4*)&hst[sr_][sc_];
            u32x4 w;
            w.x = (__float_as_uint(hv4.x) & ~3u) | wtv;
            w.y = (__float_as_uint(hv4.y) & ~3u) | wtv;
            w.z = (__float_as_uint(hv4.z) & ~3u) | wtv;
            w.w = (__float_as_uint(hv4.w) & ~3u) | wtv;
            tg_store4(hn_t + (size_t)(b0 + sr_) * HID + hct * 16 + sc_, w);
        }

        // early poll issue for t+1 (hidden under x-shadow)
        tg_load1_async(hn_t + (size_t)(b0 + prw) * HID + pc0, va);

        // shadow: x-part(t+1)
#pragma unroll
        for (int b = 0; b < 4; ++b) { xsr[b] = 0.f; xsz[b] = 0.f; xsn[b] = 0.f; }
#pragma unroll
        for (int b = 0; b < 4; ++b)
#pragma unroll
            for (int j = 0; j < 8; ++j) {
                float4 xv = *(const float4*)&xlds[(t + 1) & 1][b][j * 64 + ks4];
                ACC4(xsr[b], &Wx[0][4 * j], xv);
                ACC4(xsz[b], &Wx[1][4 * j], xv);
                ACC4(xsn[b], &Wx[2][4 * j], xv);
            }
#pragma unroll
        for (int m = 1; m <= 8; m <<= 1)
#pragma unroll
            for (int b = 0; b < 4; ++b) {
                xsr[b] += __shfl_xor(xsr[b], m, 64);
                xsz[b] += __shfl_xor(xsz[b], m, 64);
                xsn[b] += __shfl_xor(xsn[b], m, 64);
            }
    }
}

// ---------------- L1 backward: only t=T-1 consumed -> one step from h0=0 ----
__global__ __launch_bounds__(256) void l1r_laststep(
    const float* __restrict__ h1, const float* __restrict__ wih,
    const float* __restrict__ bih, const float* __restrict__ bhh,
    float* __restrict__ h2b)
{
    const int tid = threadIdx.x;
    const int b  = (blockIdx.x >> 4) * 16 + (tid >> 4);
    const int hc = (blockIdx.x & 15) * 16 + (tid & 15);
    const float* hrow = h1 + ((size_t)b * T_SZ + (T_SZ - 1)) * H2;
    float ar = 0.f, az = 0.f, an = 0.f;
#pragma unroll 8
    for (int k = 0; k < H2; k += 4) {
        float4 hv = *(const float4*)(hrow + k);
        float4 wr = *(const float4*)(wih + (size_t)hc * H2 + k);
        float4 wz = *(const float4*)(wih + (size_t)(HID + hc) * H2 + k);
        float4 wn = *(const float4*)(wih + (size_t)(2 * HID + hc) * H2 + k);
        ar = fmaf(hv.x, wr.x, fmaf(hv.y, wr.y, fmaf(hv.z, wr.z, fmaf(hv.w, wr.w, ar))));
        az = fmaf(hv.x, wz.x, fmaf(hv.y, wz.y, fmaf(hv.z, wz.z, fmaf(hv.w, wz.w, az))));
        an = fmaf(hv.x, wn.x, fmaf(hv.y, wn.y, fmaf(hv.z, wn.z, fmaf(hv.w, wn.w, an))));
    }
    float r = 1.f / (1.f + expf(-(ar + bih[hc] + bhh[hc])));
    float z = 1.f / (1.f + expf(-(az + bih[HID + hc] + bhh[HID + hc])));
    float n = tanhf(an + bih[2 * HID + hc] + r * bhh[2 * HID + hc]);
    h2b[(size_t)b * HID + hc] = (1.f - z) * n;
}

// ---------------- LayerNorm + head ----------------
__global__ __launch_bounds__(256) void ln_head(
    const float* __restrict__ h2f, const float* __restrict__ h2b,
    const float* __restrict__ g, const float* __restrict__ be,
    const float* __restrict__ hw, const float* __restrict__ hb,
    float* __restrict__ out)
{
    __shared__ float v[H2];
    __shared__ float rbuf[8];
    const int b = blockIdx.x, tid = threadIdx.x;
    float xa = h2f[(size_t)b * HID + tid];
    float xb = h2b[(size_t)b * HID + tid];
    float s = xa + xb;
#pragma unroll
    for (int m = 32; m >= 1; m >>= 1) s += __shfl_xor(s, m, 64);
    if ((tid & 63) == 0) rbuf[tid >> 6] = s;
    __syncthreads();
    float mu = (rbuf[0] + rbuf[1] + rbuf[2] + rbuf[3]) * (1.0f / H2);
    float da = xa - mu, db = xb - mu;
    float q = da * da + db * db;
#pragma unroll
    for (int m = 32; m >= 1; m >>= 1) q += __shfl_xor(q, m, 64);
    __syncthreads();
    if ((tid & 63) == 0) rbuf[tid >> 6] = q;
    __syncthreads();
    float var = (rbuf[0] + rbuf[1] + rbuf[2] + rbuf[3]) * (1.0f / H2);
    float rs = rsqrtf(var + 1e-5f);
    v[tid]       = da * rs * g[tid] + be[tid];
    v[HID + tid] = db * rs * g[HID + tid] + be[HID + tid];
    __syncthreads();
    if (tid < NCLS) {
        float a = hb[tid];
        const float* wr = hw + (size_t)tid * H2;
#pragma unroll 4
        for (int k = 0; k < H2; k += 4) {
            float4 wv = *(const float4*)(wr + k);
            a = fmaf(v[k], wv.x, fmaf(v[k + 1], wv.y, fmaf(v[k + 2], wv.z, fmaf(v[k + 3], wv.w, a))));
        }
        out[(size_t)b * NCLS + tid] = a;
    }
}

// ---------------- host ----------------
extern "C" void kernel_launch(void* const* d_in, const int* in_sizes, int n_in,
                              void* d_out, int out_size, void* d_ws, size_t ws_size,
                              hipStream_t stream)
{
    const float* x     = (const float*)d_in[0];
    const float* wih0f = (const float*)d_in[1];
    const float* whh0f = (const float*)d_in[2];
    const float* bih0f = (const float*)d_in[3];
    const float* bhh0f = (const float*)d_in[4];
    const float* wih0b = (const float*)d_in[5];
    const float* whh0b = (const float*)d_in[6];
    const float* bih0b = (const float*)d_in[7];
    const float* bhh0b = (const float*)d_in[8];
    const float* wih1f = (const float*)d_in[9];
    const float* whh1f = (const float*)d_in[10];
    const float* bih1f = (const float*)d_in[11];
    const float* bhh1f = (const float*)d_in[12];
    const float* wih1b = (const float*)d_in[13];
    const float* whh1b = (const float*)d_in[14];
    const float* bih1b = (const float*)d_in[15];
    const float* bhh1b = (const float*)d_in[16];
    const float* lng   = (const float*)d_in[17];
    const float* lnb   = (const float*)d_in[18];
    const float* hw    = (const float*)d_in[19];
    const float* hbb   = (const float*)d_in[20];

    char* wsb = (char*)d_ws;
    size_t off = 0;
    auto alloc = [&](size_t bytes) -> void* {
        void* p = (void*)(wsb + off);
        off += (bytes + 255) & ~(size_t)255;
        return p;
    };
    unsigned* thbA = (unsigned*)alloc((size_t)2 * 2 * B_SZ * HID * 4);   // 1 MB tagged
    unsigned* thbB = (unsigned*)alloc((size_t)2 * B_SZ * HID * 4);       // 512 KB tagged
    size_t zspan = off;
    float* h2b = (float*)alloc((size_t)B_SZ * HID * 4);
    float* h1  = (float*)alloc((size_t)B_SZ * T_SZ * H2 * 4);            // 64 MB

    // zero tagged buffers: tag 0 == "h(0)=0 valid" (re-runs on every replay)
    (void)hipMemsetAsync(d_ws, 0, zspan, stream);

    l0_scan<<<dim3(512), dim3(256), 0, stream>>>(
        x, wih0f, bih0f, whh0f, bhh0f, wih0b, bih0b, whh0b, bhh0b, thbA, h1);

    l1r_laststep<<<dim3(128), dim3(256), 0, stream>>>(h1, wih1b, bih1b, bhh1b, h2b);

    l1_scan<<<dim3(512), dim3(256), 0, stream>>>(
        h1, wih1f, bih1f, whh1f, bhh1f, thbB);

    // L1-fwd final h lands in parity 0 (t=255 writes (255+1)&1 == 0); tags are 0 bits
    ln_head<<<dim3(B_SZ), dim3(256), 0, stream>>>(
        (const float*)thbB, h2b, lng, lnb, hw, hbb, (float*)d_out);
}

// Round 16
// 2772.550 us; speedup vs baseline: 1.2904x; 1.0242x over previous
//
#include <hip/hip_runtime.h>
#include <math.h>

#define B_SZ 128
#define T_SZ 256
#define DIN  128
#define HID  256
#define H2   512
#define NCLS 250

typedef float    f32x4 __attribute__((ext_vector_type(4)));
typedef unsigned u32x4 __attribute__((ext_vector_type(4)));

// ---- device-coherent 16B ops (sc0 sc1 = proven agent visibility) ----------
__device__ __forceinline__ void tg_load1(const unsigned* p, u32x4& a) {
    asm volatile("global_load_dwordx4 %0, %1, off sc0 sc1\n\t"
                 "s_waitcnt vmcnt(0)"
                 : "=&v"(a) : "v"(p) : "memory");
}
// two 16B spans 512B apart (l0 poll map: cols c..c+3 and c+128..c+131)
__device__ __forceinline__ void tg_load2_split(const unsigned* p, u32x4& a, u32x4& b) {
    asm volatile("global_load_dwordx4 %0, %2, off sc0 sc1\n\t"
                 "global_load_dwordx4 %1, %2, off offset:512 sc0 sc1\n\t"
                 "s_waitcnt vmcnt(0)"
                 : "=&v"(a), "=&v"(b) : "v"(p) : "memory");
}
__device__ __forceinline__ void tg_store4(unsigned* p, u32x4 v) {
    asm volatile("global_store_dwordx4 %0, %1, off sc0 sc1" :: "v"(p), "v"(v) : "memory");
}

#define ACC4(A, Wp, v) \
    A = fmaf((v).x, (Wp)[0], A); A = fmaf((v).y, (Wp)[1], A); \
    A = fmaf((v).z, (Wp)[2], A); A = fmaf((v).w, (Wp)[3], A)

// 512 WGs: XCD slot = wg&7; member = (wg>>3)&15; group = (wg&7)*4 + (wg>>7).
// 32 groups x 16 members; each group pinned to one XCD slot (perf heuristic).
__device__ __forceinline__ void group_decode(int wg, int& g, int& member) {
    member = (wg >> 3) & 15;
    g = (wg & 7) * 4 + (wg >> 7);
}

// ---------------- L0: one dir per WG, 8-row groups, fused x-GEMM ------------
// 32 groups = dir(2) x bt(16 tiles of 8 rows); member = hct (16 cols).
__global__ __launch_bounds__(256, 2) void l0_scan(
    const float* __restrict__ x,
    const float* __restrict__ wihf, const float* __restrict__ bihf,
    const float* __restrict__ whhf, const float* __restrict__ bhhf,
    const float* __restrict__ wihb, const float* __restrict__ bihb,
    const float* __restrict__ whhb, const float* __restrict__ bhhb,
    unsigned* __restrict__ thb,   // [2 dir][2 par][B][HID] tagged
    float* __restrict__ h1)       // [B][T][512]
{
    __shared__ float hlds[8][256];
    __shared__ float xlds[2][8][128];
    __shared__ float hst[8][20];
    const int tid = threadIdx.x;
    int g, member;
    group_decode(blockIdx.x, g, member);
    const int dir = g >> 4;
    const int b0  = (g & 15) * 8;
    const int hct = member;
    const int hc = tid >> 4, ks = tid & 15, ks4 = ks * 4;
    const int hcg = hct * 16 + hc;

    const float* wih = dir ? wihb : wihf;
    const float* bih = dir ? bihb : bihf;
    const float* whh = dir ? whhb : whhf;
    const float* bhh = dir ? bhhb : bhhf;

    float Wr[3][16], Wx[3][8];
#pragma unroll
    for (int gg = 0; gg < 3; ++gg) {
#pragma unroll
        for (int j = 0; j < 4; ++j) {
            float4 wv = *(const float4*)(whh + (size_t)(gg * HID + hcg) * HID + j * 64 + ks4);
            Wr[gg][4 * j] = wv.x; Wr[gg][4 * j + 1] = wv.y; Wr[gg][4 * j + 2] = wv.z; Wr[gg][4 * j + 3] = wv.w;
        }
#pragma unroll
        for (int j = 0; j < 2; ++j) {
            float4 wv = *(const float4*)(wih + (size_t)(gg * HID + hcg) * DIN + j * 64 + ks4);
            Wx[gg][4 * j] = wv.x; Wx[gg][4 * j + 1] = wv.y; Wx[gg][4 * j + 2] = wv.z; Wx[gg][4 * j + 3] = wv.w;
        }
    }
    const float sbr = bih[hcg] + bhh[hcg];
    const float sbz = bih[HID + hcg] + bhh[HID + hcg];
    const float bxn = bih[2 * HID + hcg];
    const float bhn = bhh[2 * HID + hcg];

    unsigned* hb = thb + (size_t)dir * 2 * B_SZ * HID;
    const int r8 = tid >> 5, c32 = (tid & 31) * 4;   // x-staging (8x128, 16B/thr)
    const int prow = tid >> 5, pc4 = (tid & 31) * 4; // h poll: 16B at +0 and +512B

    // ---- prologue: stage x(0), prefetch x(1), xsum(0)
    float4 xp;
    {
        const int tg0 = dir ? (T_SZ - 1) : 0;
        xp = *(const float4*)(x + ((size_t)(b0 + r8) * T_SZ + tg0) * DIN + c32);
        *(float4*)&xlds[0][r8][c32] = xp;
    }
    __syncthreads();
    {
        const int tg1 = dir ? (T_SZ - 2) : 1;
        xp = *(const float4*)(x + ((size_t)(b0 + r8) * T_SZ + tg1) * DIN + c32);
    }
    float xsr[8], xsz[8], xsn[8];
#pragma unroll
    for (int b = 0; b < 8; ++b) { xsr[b] = 0.f; xsz[b] = 0.f; xsn[b] = 0.f; }
#pragma unroll
    for (int b = 0; b < 8; ++b)
#pragma unroll
        for (int j = 0; j < 2; ++j) {
            float4 xv = *(const float4*)&xlds[0][b][j * 64 + ks4];
            ACC4(xsr[b], &Wx[0][4 * j], xv);
            ACC4(xsz[b], &Wx[1][4 * j], xv);
            ACC4(xsn[b], &Wx[2][4 * j], xv);
        }
#pragma unroll
    for (int m = 1; m <= 8; m <<= 1)
#pragma unroll
        for (int b = 0; b < 8; ++b) {
            xsr[b] += __shfl_xor(xsr[b], m, 64);
            xsz[b] += __shfl_xor(xsz[b], m, 64);
            xsn[b] += __shfl_xor(xsn[b], m, 64);
        }

    for (int t = 0; t < T_SZ; ++t) {
        const int tg = dir ? (T_SZ - 1 - t) : t;
        const unsigned* hp_t = hb + (size_t)(t & 1) * B_SZ * HID;
        unsigned* hn_t       = hb + (size_t)((t + 1) & 1) * B_SZ * HID;
        const unsigned tgv = (unsigned)(t & 3);
        const unsigned wtv = (unsigned)((t + 1) & 3);

        {   // tagged poll: own 2x16B spans (cols pc4, pc4+128)
            const unsigned* pp = hp_t + (size_t)(b0 + prow) * HID + pc4;
            u32x4 va, vb;
            for (;;) {
                tg_load2_split(pp, va, vb);
                unsigned m = (va.x^tgv)|(va.y^tgv)|(va.z^tgv)|(va.w^tgv)
                           | (vb.x^tgv)|(vb.y^tgv)|(vb.z^tgv)|(vb.w^tgv);
                if ((m & 3u) == 0u) break;
            }
            *(u32x4*)&hlds[prow][pc4]       = va;
            *(u32x4*)&hlds[prow][pc4 + 128] = vb;
        }
        *(float4*)&xlds[(t + 1) & 1][r8][c32] = xp;   // stage x(t+1)
        __syncthreads();                               // SYNC1

        {   // prefetch x(t+2)
            const int tn  = (t + 2 < T_SZ) ? (t + 2) : (T_SZ - 1);
            const int tgn = dir ? (T_SZ - 1 - tn) : tn;
            xp = *(const float4*)(x + ((size_t)(b0 + r8) * T_SZ + tgn) * DIN + c32);
        }

        float aR[8], aZ[8], aH[8];
#pragma unroll
        for (int b = 0; b < 8; ++b) { aR[b] = 0.f; aZ[b] = 0.f; aH[b] = 0.f; }
#pragma unroll
        for (int b = 0; b < 8; ++b)
#pragma unroll
            for (int j = 0; j < 4; ++j) {
                float4 hv4 = *(const float4*)&hlds[b][j * 64 + ks4];
                ACC4(aR[b], &Wr[0][4 * j], hv4);
                ACC4(aZ[b], &Wr[1][4 * j], hv4);
                ACC4(aH[b], &Wr[2][4 * j], hv4);
            }
#pragma unroll
        for (int m = 1; m <= 8; m <<= 1)
#pragma unroll
            for (int b = 0; b < 8; ++b) {
                aR[b] += __shfl_xor(aR[b], m, 64);
                aZ[b] += __shfl_xor(aZ[b], m, 64);
                aH[b] += __shfl_xor(aH[b], m, 64);
            }

        if (ks < 8) {   // lane ks owns batch row b0+ks
            float sr = 0.f, sz = 0.f, sh = 0.f, xr = 0.f, xz = 0.f, xn = 0.f;
#pragma unroll
            for (int b = 0; b < 8; ++b)
                if (b == ks) { sr = aR[b]; sz = aZ[b]; sh = aH[b];
                               xr = xsr[b]; xz = xsz[b]; xn = xsn[b]; }
            const float hp = hlds[ks][hcg];
            const float r = 1.f / (1.f + expf(-(sr + xr + sbr)));
            const float z = 1.f / (1.f + expf(-(sz + xz + sbz)));
            const float n = tanhf(xn + bxn + r * (sh + bhn));
            hst[ks][hc] = (1.f - z) * n + z * hp;
        }
        __syncthreads();                               // SYNC2
        if (tid < 32) {   // pack tagged h-state (8x16) + h1 store
            const int sr_ = tid >> 2, sc_ = (tid & 3) * 4;
            float4 hv4 = *(const float4*)&hst[sr_][sc_];
            u32x4 w;
            w.x = (__float_as_uint(hv4.x) & ~3u) | wtv;
            w.y = (__float_as_uint(hv4.y) & ~3u) | wtv;
            w.z = (__float_as_uint(hv4.z) & ~3u) | wtv;
            w.w = (__float_as_uint(hv4.w) & ~3u) | wtv;
            tg_store4(hn_t + (size_t)(b0 + sr_) * HID + hct * 16 + sc_, w);
            *(float4*)(h1 + ((size_t)(b0 + sr_) * T_SZ + tg) * H2 + dir * HID + hct * 16 + sc_) = hv4;
        }

        // shadow: xsum(t+1) (hides store visibility latency)
#pragma unroll
        for (int b = 0; b < 8; ++b) { xsr[b] = 0.f; xsz[b] = 0.f; xsn[b] = 0.f; }
#pragma unroll
        for (int b = 0; b < 8; ++b)
#pragma unroll
            for (int j = 0; j < 2; ++j) {
                float4 xv = *(const float4*)&xlds[(t + 1) & 1][b][j * 64 + ks4];
                ACC4(xsr[b], &Wx[0][4 * j], xv);
                ACC4(xsz[b], &Wx[1][4 * j], xv);
                ACC4(xsn[b], &Wx[2][4 * j], xv);
            }
#pragma unroll
        for (int m = 1; m <= 8; m <<= 1)
#pragma unroll
            for (int b = 0; b < 8; ++b) {
                xsr[b] += __shfl_xor(xsr[b], m, 64);
                xsz[b] += __shfl_xor(xsz[b], m, 64);
                xsn[b] += __shfl_xor(xsn[b], m, 64);
            }
    }
}

// ---------------- L1 forward: 4-row groups, fused x-GEMM (Din=512) ----------
// 32 groups = bt(32 tiles of 4 rows); member = hct.
__global__ __launch_bounds__(256, 2) void l1_scan(
    const float* __restrict__ h1,
    const float* __restrict__ wih, const float* __restrict__ bih,
    const float* __restrict__ whh, const float* __restrict__ bhh,
    unsigned* __restrict__ thb)   // [2 par][B][HID] tagged
{
    __shared__ float hlds[4][256];
    __shared__ float xlds[2][4][512];
    __shared__ float hst[4][20];
    const int tid = threadIdx.x;
    int g, member;
    group_decode(blockIdx.x, g, member);
    const int b0  = g * 4;
    const int hct = member;
    const int hc = tid >> 4, ks = tid & 15, ks4 = ks * 4;
    const int hcg = hct * 16 + hc;

    float Wr[3][16], Wx[3][32];
#pragma unroll
    for (int gg = 0; gg < 3; ++gg) {
#pragma unroll
        for (int j = 0; j < 4; ++j) {
            float4 wv = *(const float4*)(whh + (size_t)(gg * HID + hcg) * HID + j * 64 + ks4);
            Wr[gg][4 * j] = wv.x; Wr[gg][4 * j + 1] = wv.y; Wr[gg][4 * j + 2] = wv.z; Wr[gg][4 * j + 3] = wv.w;
        }
#pragma unroll
        for (int j = 0; j < 8; ++j) {
            float4 wv = *(const float4*)(wih + (size_t)(gg * HID + hcg) * H2 + j * 64 + ks4);
            Wx[gg][4 * j] = wv.x; Wx[gg][4 * j + 1] = wv.y; Wx[gg][4 * j + 2] = wv.z; Wx[gg][4 * j + 3] = wv.w;
        }
    }
    const float sbr = bih[hcg] + bhh[hcg];
    const float sbz = bih[HID + hcg] + bhh[HID + hcg];
    const float bxn = bih[2 * HID + hcg];
    const float bhn = bhh[2 * HID + hcg];

    const int r4 = tid >> 6, s64 = (tid & 63) * 4;   // x-staging (4x512, 2x16B/thr)
    const int prw = tid >> 6, pc0 = (tid & 63) * 4;  // h poll (4x256, 16B/thr)

    float4 xp[2];
    {
        const float* xsrc = h1 + ((size_t)(b0 + r4) * T_SZ + 0) * H2;
        xp[0] = *(const float4*)(xsrc + s64);
        xp[1] = *(const float4*)(xsrc + 256 + s64);
        *(float4*)&xlds[0][r4][s64]       = xp[0];
        *(float4*)&xlds[0][r4][256 + s64] = xp[1];
    }
    __syncthreads();
    {
        const float* xsrc = h1 + ((size_t)(b0 + r4) * T_SZ + 1) * H2;
        xp[0] = *(const float4*)(xsrc + s64);
        xp[1] = *(const float4*)(xsrc + 256 + s64);
    }
    float xsr[4], xsz[4], xsn[4];
#pragma unroll
    for (int b = 0; b < 4; ++b) { xsr[b] = 0.f; xsz[b] = 0.f; xsn[b] = 0.f; }
#pragma unroll
    for (int b = 0; b < 4; ++b)
#pragma unroll
        for (int j = 0; j < 8; ++j) {
            float4 xv = *(const float4*)&xlds[0][b][j * 64 + ks4];
            ACC4(xsr[b], &Wx[0][4 * j], xv);
            ACC4(xsz[b], &Wx[1][4 * j], xv);
            ACC4(xsn[b], &Wx[2][4 * j], xv);
        }
#pragma unroll
    for (int m = 1; m <= 8; m <<= 1)
#pragma unroll
        for (int b = 0; b < 4; ++b) {
            xsr[b] += __shfl_xor(xsr[b], m, 64);
            xsz[b] += __shfl_xor(xsz[b], m, 64);
            xsn[b] += __shfl_xor(xsn[b], m, 64);
        }

    for (int t = 0; t < T_SZ; ++t) {
        const unsigned* hp_t = thb + (size_t)(t & 1) * B_SZ * HID;
        unsigned* hn_t       = thb + (size_t)((t + 1) & 1) * B_SZ * HID;
        const unsigned tgv = (unsigned)(t & 3);
        const unsigned wtv = (unsigned)((t + 1) & 3);

        {   // tagged poll: own 4 h values (16B)
            const unsigned* pp = hp_t + (size_t)(b0 + prw) * HID + pc0;
            u32x4 va;
            for (;;) {
                tg_load1(pp, va);
                unsigned m = (va.x^tgv)|(va.y^tgv)|(va.z^tgv)|(va.w^tgv);
                if ((m & 3u) == 0u) break;
            }
            *(u32x4*)&hlds[prw][pc0] = va;
        }
        *(float4*)&xlds[(t + 1) & 1][r4][s64]       = xp[0];
        *(float4*)&xlds[(t + 1) & 1][r4][256 + s64] = xp[1];
        __syncthreads();                               // SYNC1

        {   // prefetch x(t+2) from h1
            const int tn = (t + 2 < T_SZ) ? (t + 2) : (T_SZ - 1);
            const float* xsrc = h1 + ((size_t)(b0 + r4) * T_SZ + tn) * H2;
            xp[0] = *(const float4*)(xsrc + s64);
            xp[1] = *(const float4*)(xsrc + 256 + s64);
        }

        float aR[4], aZ[4], aH[4];
#pragma unroll
        for (int b = 0; b < 4; ++b) { aR[b] = 0.f; aZ[b] = 0.f; aH[b] = 0.f; }
#pragma unroll
        for (int b = 0; b < 4; ++b)
#pragma unroll
            for (int j = 0; j < 4; ++j) {
                float4 hv4 = *(const float4*)&hlds[b][j * 64 + ks4];
                ACC4(aR[b], &Wr[0][4 * j], hv4);
                ACC4(aZ[b], &Wr[1][4 * j], hv4);
                ACC4(aH[b], &Wr[2][4 * j], hv4);
            }
#pragma unroll
        for (int m = 1; m <= 8; m <<= 1)
#pragma unroll
            for (int b = 0; b < 4; ++b) {
                aR[b] += __shfl_xor(aR[b], m, 64);
                aZ[b] += __shfl_xor(aZ[b], m, 64);
                aH[b] += __shfl_xor(aH[b], m, 64);
            }

        if (ks < 4) {   // lane ks owns row b0+ks
            float sr = 0.f, sz = 0.f, sh = 0.f, xr = 0.f, xz = 0.f, xn = 0.f;
#pragma unroll
            for (int b = 0; b < 4; ++b)
                if (b == ks) { sr = aR[b]; sz = aZ[b]; sh = aH[b];
                               xr = xsr[b]; xz = xsz[b]; xn = xsn[b]; }
            const float hp = hlds[ks][hcg];
            const float r = 1.f / (1.f + expf(-(sr + xr + sbr)));
            const float z = 1.f / (1.f + expf(-(sz + xz + sbz)));
            const float n = tanhf(xn + bxn + r * (sh + bhn));
            hst[ks][hc] = (1.f - z) * n + z * hp;
        }
        __syncthreads();                               // SYNC2
        if (tid < 16) {   // pack tagged h-state (4x16)
            const int sr_ = tid >> 2, sc_ = (tid & 3) * 4;
            float4 hv4 = *(const float4*)&hst[sr_][sc_];
            u32x4 w;
            w.x = (__float_as_uint(hv4.x) & ~3u) | wtv;
            w.y = (__float_as_uint(hv4.y) & ~3u) | wtv;
            w.z = (__float_as_uint(hv4.z) & ~3u) | wtv;
            w.w = (__float_as_uint(hv4.w) & ~3u) | wtv;
            tg_store4(hn_t + (size_t)(b0 + sr_) * HID + hct * 16 + sc_, w);
        }

        // shadow: x-part(t+1)
#pragma unroll
        for (int b = 0; b < 4; ++b) { xsr[b] = 0.f; xsz[b] = 0.f; xsn[b] = 0.f; }
#pragma unroll
        for (int b = 0; b < 4; ++b)
#pragma unroll
            for (int j = 0; j < 8; ++j) {
                float4 xv = *(const float4*)&xlds[(t + 1) & 1][b][j * 64 + ks4];
                ACC4(xsr[b], &Wx[0][4 * j], xv);
                ACC4(xsz[b], &Wx[1][4 * j], xv);
                ACC4(xsn[b], &Wx[2][4 * j], xv);
            }
#pragma unroll
        for (int m = 1; m <= 8; m <<= 1)
#pragma unroll
            for (int b = 0; b < 4; ++b) {
                xsr[b] += __shfl_xor(xsr[b], m, 64);
                xsz[b] += __shfl_xor(xsz[b], m, 64);
                xsn[b] += __shfl_xor(xsn[b], m, 64);
            }
    }
}

// ---------------- L1 backward: only t=T-1 consumed -> one step from h0=0 ----
__global__ __launch_bounds__(256) void l1r_laststep(
    const float* __restrict__ h1, const float* __restrict__ wih,
    const float* __restrict__ bih, const float* __restrict__ bhh,
    float* __restrict__ h2b)
{
    const int tid = threadIdx.x;
    const int b  = (blockIdx.x >> 4) * 16 + (tid >> 4);
    const int hc = (blockIdx.x & 15) * 16 + (tid & 15);
    const float* hrow = h1 + ((size_t)b * T_SZ + (T_SZ - 1)) * H2;
    float ar = 0.f, az = 0.f, an = 0.f;
#pragma unroll 8
    for (int k = 0; k < H2; k += 4) {
        float4 hv = *(const float4*)(hrow + k);
        float4 wr = *(const float4*)(wih + (size_t)hc * H2 + k);
        float4 wz = *(const float4*)(wih + (size_t)(HID + hc) * H2 + k);
        float4 wn = *(const float4*)(wih + (size_t)(2 * HID + hc) * H2 + k);
        ar = fmaf(hv.x, wr.x, fmaf(hv.y, wr.y, fmaf(hv.z, wr.z, fmaf(hv.w, wr.w, ar))));
        az = fmaf(hv.x, wz.x, fmaf(hv.y, wz.y, fmaf(hv.z, wz.z, fmaf(hv.w, wz.w, az))));
        an = fmaf(hv.x, wn.x, fmaf(hv.y, wn.y, fmaf(hv.z, wn.z, fmaf(hv.w, wn.w, an))));
    }
    float r = 1.f / (1.f + expf(-(ar + bih[hc] + bhh[hc])));
    float z = 1.f / (1.f + expf(-(az + bih[HID + hc] + bhh[HID + hc])));
    float n = tanhf(an + bih[2 * HID + hc] + r * bhh[2 * HID + hc]);
    h2b[(size_t)b * HID + hc] = (1.f - z) * n;
}

// ---------------- LayerNorm + head ----------------
__global__ __launch_bounds__(256) void ln_head(
    const float* __restrict__ h2f, const float* __restrict__ h2b,
    const float* __restrict__ g, const float* __restrict__ be,
    const float* __restrict__ hw, const float* __restrict__ hb,
    float* __restrict__ out)
{
    __shared__ float v[H2];
    __shared__ float rbuf[8];
    const int b = blockIdx.x, tid = threadIdx.x;
    float xa = h2f[(size_t)b * HID + tid];
    float xb = h2b[(size_t)b * HID + tid];
    float s = xa + xb;
#pragma unroll
    for (int m = 32; m >= 1; m >>= 1) s += __shfl_xor(s, m, 64);
    if ((tid & 63) == 0) rbuf[tid >> 6] = s;
    __syncthreads();
    float mu = (rbuf[0] + rbuf[1] + rbuf[2] + rbuf[3]) * (1.0f / H2);
    float da = xa - mu, db = xb - mu;
    float q = da * da + db * db;
#pragma unroll
    for (int m = 32; m >= 1; m >>= 1) q += __shfl_xor(q, m, 64);
    __syncthreads();
    if ((tid & 63) == 0) rbuf[tid >> 6] = q;
    __syncthreads();
    float var = (rbuf[0] + rbuf[1] + rbuf[2] + rbuf[3]) * (1.0f / H2);
    float rs = rsqrtf(var + 1e-5f);
    v[tid]       = da * rs * g[tid] + be[tid];
    v[HID + tid] = db * rs * g[HID + tid] + be[HID + tid];
    __syncthreads();
    if (tid < NCLS) {
        float a = hb[tid];
        const float* wr = hw + (size_t)tid * H2;
#pragma unroll 4
        for (int k = 0; k < H2; k += 4) {
            float4 wv = *(const float4*)(wr + k);
            a = fmaf(v[k], wv.x, fmaf(v[k + 1], wv.y, fmaf(v[k + 2], wv.z, fmaf(v[k + 3], wv.w, a))));
        }
        out[(size_t)b * NCLS + tid] = a;
    }
}

// ---------------- host ----------------
extern "C" void kernel_launch(void* const* d_in, const int* in_sizes, int n_in,
                              void* d_out, int out_size, void* d_ws, size_t ws_size,
                              hipStream_t stream)
{
    const float* x     = (const float*)d_in[0];
    const float* wih0f = (const float*)d_in[1];
    const float* whh0f = (const float*)d_in[2];
    const float* bih0f = (const float*)d_in[3];
    const float* bhh0f = (const float*)d_in[4];
    const float* wih0b = (const float*)d_in[5];
    const float* whh0b = (const float*)d_in[6];
    const float* bih0b = (const float*)d_in[7];
    const float* bhh0b = (const float*)d_in[8];
    const float* wih1f = (const float*)d_in[9];
    const float* whh1f = (const float*)d_in[10];
    const float* bih1f = (const float*)d_in[11];
    const float* bhh1f = (const float*)d_in[12];
    const float* wih1b = (const float*)d_in[13];
    const float* whh1b = (const float*)d_in[14];
    const float* bih1b = (const float*)d_in[15];
    const float* bhh1b = (const float*)d_in[16];
    const float* lng   = (const float*)d_in[17];
    const float* lnb   = (const float*)d_in[18];
    const float* hw    = (const float*)d_in[19];
    const float* hbb   = (const float*)d_in[20];

    char* wsb = (char*)d_ws;
    size_t off = 0;
    auto alloc = [&](size_t bytes) -> void* {
        void* p = (void*)(wsb + off);
        off += (bytes + 255) & ~(size_t)255;
        return p;
    };
    unsigned* thbA = (unsigned*)alloc((size_t)2 * 2 * B_SZ * HID * 4);   // 1 MB tagged
    unsigned* thbB = (unsigned*)alloc((size_t)2 * B_SZ * HID * 4);       // 512 KB tagged
    size_t zspan = off;
    float* h2b = (float*)alloc((size_t)B_SZ * HID * 4);
    float* h1  = (float*)alloc((size_t)B_SZ * T_SZ * H2 * 4);            // 64 MB

    // zero tagged buffers: tag 0 == "h(0)=0 valid" (re-runs on every replay)
    (void)hipMemsetAsync(d_ws, 0, zspan, stream);

    // plain launches; 512 WGs resident by capacity (VGPR<=256 -> 2 blocks/CU)
    l0_scan<<<dim3(512), dim3(256), 0, stream>>>(
        x, wih0f, bih0f, whh0f, bhh0f, wih0b, bih0b, whh0b, bhh0b, thbA, h1);

    l1r_laststep<<<dim3(128), dim3(256), 0, stream>>>(h1, wih1b, bih1b, bhh1b, h2b);

    l1_scan<<<dim3(512), dim3(256), 0, stream>>>(
        h1, wih1f, bih1f, whh1f, bhh1f, thbB);

    // L1-fwd final h lands in parity 0 (t=255 writes (255+1)&1 == 0); tags are 0 bits
    ln_head<<<dim3(B_SZ), dim3(256), 0, stream>>>(
        (const float*)thbB, h2b, lng, lnb, hw, hbb, (float*)d_out);
}